// Round 11
// baseline (1032.000 us; speedup 1.0000x reference)
//
#include <hip/hip_runtime.h>

#define N_NODES 50000
#define N_EDGES 800000
#define IN_F    128
#define OUT_F   128
#define NEIG    64
#define HDIM    128
#define BN_EPSF 1e-5f
#define SCAN_BLK 49              // ceil(50000/1024)
#define HSP_BLOCKS 521           // 521*96 >= 50000
#define HSP_NODES 96
#define RED_CHUNK 33             // ceil(521/16)
#define RED_SPLIT 16
#define NCHUNKS 3125             // 50000 / 16 nodes per chunk
#define GATHER_BLOCKS 2048

typedef __attribute__((ext_vector_type(8))) short short8;
typedef __attribute__((ext_vector_type(4))) float floatx4;

// ---- workspace layout (in 4-byte units) ----
// XS: 20 chunks x [N][32] bf16. chunk = GEMM K-tile index:
//   0-3 = X0 slices, 4-7 = X1, 8-11 = X2, 12-15 = X3, 16-19 = hs
#define N32        ((size_t)N_NODES * 32)
#define OFF_XS      0                                   // 20*50000*32 ushort = 16,000,000 floats
#define OFF_PART    16000000                            // 521*8192 = 4,268,032 floats
#define OFF_WT      (OFF_PART + HSP_BLOCKS * 8192)     // 40,960 floats
#define OFF_DSQRT   (OFF_WT + 40960)
#define OFF_HS      (OFF_DSQRT + N_NODES)               // 8192
#define OFF_EF      (OFF_HS + 8192)                     // 64
#define OFF_COLSUM  (OFF_EF + NEIG)                     // 128
#define OFF_COLSQ   (OFF_COLSUM + OUT_F)                // 128
#define OFF_CUR     (OFF_COLSQ + OUT_F)                 // 16 (12 cursors, padded)
#define OFF_DEG     (OFF_CUR + 16)
#define OFF_ROWSTART (OFF_DEG + N_NODES)
#define OFF_CSR     (OFF_ROWSTART + N_NODES + 1)
#define OFF_BSUM    (OFF_CSR + N_EDGES)                 // 64
#define OFF_RANK    (OFF_BSUM + 64)                     // E ints
#define ZERO_SMALL  (8192 + NEIG + 2 * OUT_F + 16)      // hs+ef+colsum+colsq+cursors = 8528
// end ~= 22.07M floats ~= 88 MB

static __device__ inline unsigned short f2bf(float f) {
    union { float f; unsigned int u; } v; v.f = f;
    unsigned int r = (v.u + 0x7FFFu + ((v.u >> 16) & 1u)) >> 16;
    return (unsigned short)r;
}
static __device__ inline float bf2f(unsigned int u16) {
    union { unsigned int u; float f; } v; v.u = u16 << 16;
    return v.f;
}

// merged: feat->X0 slice-major bf16 (blocks 0..3124) | wt (3125..3444) | zero (3445..3673)
__global__ __launch_bounds__(256) void k_prep(const float* __restrict__ feat,
                                              const float* __restrict__ W,
                                              unsigned short* __restrict__ XS,
                                              unsigned short* __restrict__ Wt,
                                              int* __restrict__ deg,
                                              float* __restrict__ small) {
    int b = blockIdx.x;
    if (b < 3125) {
        int t = b * 256 + threadIdx.x;           // [0, 800000)
        int n = t >> 4, c8 = (t & 15) * 8;       // c8 in {0,8,...,120}
        float4 a = *(const float4*)&feat[n * IN_F + c8];
        float4 bb = *(const float4*)&feat[n * IN_F + c8 + 4];
        ushort4 o0, o1;
        o0.x = f2bf(a.x); o0.y = f2bf(a.y); o0.z = f2bf(a.z); o0.w = f2bf(a.w);
        o1.x = f2bf(bb.x); o1.y = f2bf(bb.y); o1.z = f2bf(bb.z); o1.w = f2bf(bb.w);
        int slice = c8 >> 5, within = c8 & 31;
        unsigned short* p = XS + (size_t)slice * N32 + (size_t)n * 32 + within;
        *(ushort4*)p = o0;
        *(ushort4*)(p + 4) = o1;
    } else if (b < 3445) {
        int t = (b - 3125) * 256 + threadIdx.x;  // [0, 81920)
        int k = t >> 7, n = t & 127;
        Wt[n * 640 + k] = f2bf(W[k * 128 + n]);
    } else {
        int i = (b - 3445) * 256 + threadIdx.x;
        if (i < N_NODES) deg[i] = 0;
        if (i < ZERO_SMALL) small[i] = 0.0f;
    }
}

// per-edge rank within its dst bucket (atomic); deg = counts afterwards
__global__ void k_rank(int* __restrict__ deg, const int* __restrict__ dst,
                       int* __restrict__ rank) {
    int e = blockIdx.x * 256 + threadIdx.x;
    if (e < N_EDGES) rank[e] = atomicAdd(&deg[dst[e]], 1);
}

// ---- 3-stage parallel scan ----
__global__ __launch_bounds__(1024) void k_scan1(const int* __restrict__ deg,
                                                int* __restrict__ row_start,
                                                int* __restrict__ bsum) {
    __shared__ int sd[1024];
    int i = blockIdx.x * 1024 + threadIdx.x;
    int v = (i < N_NODES) ? deg[i] : 0;
    sd[threadIdx.x] = v;
    __syncthreads();
    for (int off = 1; off < 1024; off <<= 1) {
        int t = (threadIdx.x >= off) ? sd[threadIdx.x - off] : 0;
        __syncthreads();
        sd[threadIdx.x] += t;
        __syncthreads();
    }
    if (i < N_NODES) row_start[i] = sd[threadIdx.x] - v;
    if (threadIdx.x == 1023) bsum[blockIdx.x] = sd[1023];
}

__global__ void k_scan2(int* __restrict__ bsum) {
    int t = threadIdx.x;
    int orig = (t < SCAN_BLK) ? bsum[t] : 0;
    int v = orig;
    for (int off = 1; off < 64; off <<= 1) {
        int u = __shfl_up(v, off);
        if (t >= off) v += u;
    }
    if (t < SCAN_BLK) bsum[t] = v - orig;
}

__global__ __launch_bounds__(1024) void k_scan3(const int* __restrict__ deg,
                                                int* __restrict__ row_start,
                                                const int* __restrict__ bsum,
                                                float* __restrict__ dsq) {
    int i = blockIdx.x * 1024 + threadIdx.x;
    if (i < N_NODES) {
        int r = row_start[i] + bsum[blockIdx.x];
        row_start[i] = r;
        dsq[i] = rsqrtf((float)max(deg[i], 1));
    }
    if (i == 0) row_start[N_NODES] = N_EDGES;
}

// scatter csr entries, no atomics (rank precomputed)
__global__ void k_csr(const int* __restrict__ src, const int* __restrict__ dst,
                      const int* __restrict__ rank, const int* __restrict__ row_start,
                      int* __restrict__ csr_src) {
    int e = blockIdx.x * 256 + threadIdx.x;
    if (e < N_EDGES) csr_src[row_start[dst[e]] + rank[e]] = src[e];
}

// XCD-pinned slice-resident gather.
// slice = XCC_ID & 3 -> each XCD's randomly re-read source slice is 3.2 MB,
// L2-resident by construction. Persistent blocks pull 16-node chunks from a
// per-slice cursor; after own slice drains, steal others (correctness is
// mapping-independent). Wave = 4 edge-groups x 16 feat-lanes, 8-edge ILP.
// csr / pp / output use non-temporal ops so streams don't evict the slice.
__global__ __launch_bounds__(256) void k_gather(const int* __restrict__ row_start,
                                                const int* __restrict__ csr_src,
                                                const float* __restrict__ dsq,
                                                unsigned short* __restrict__ XS,
                                                const float* __restrict__ lm,
                                                int first, int srcC, int ppC, int outC,
                                                int* __restrict__ cursors) {
    int xcc;
    asm volatile("s_getreg_b32 %0, hwreg(HW_REG_XCC_ID)" : "=s"(xcc));
    int wv = threadIdx.x >> 6;
    int lane = threadIdx.x & 63;
    int g = lane >> 4, fl = lane & 15;
    float rn = 2.0f / lm[0];
    float bcoef = first ? (rn - 1.0f) : 2.0f * (rn - 1.0f);
    float am = first ? -rn : -2.0f * rn;
    __shared__ int s_chunk;

    for (int pass = 0; pass < 4; ++pass) {
        int slice = (xcc + pass) & 3;
        const unsigned short* srcS = XS + (size_t)(srcC + slice) * N32;
        const unsigned short* ppS  = (ppC >= 0) ? XS + (size_t)(ppC + slice) * N32 : nullptr;
        unsigned short* outS = XS + (size_t)(outC + slice) * N32;
        int* cur = &cursors[slice];
        while (true) {
            __syncthreads();
            if (threadIdx.x == 0) s_chunk = atomicAdd(cur, 1);
            __syncthreads();
            int chunk = s_chunk;
            if (chunk >= NCHUNKS) break;
            int nbase = chunk * 16 + wv * 4;
#pragma unroll
            for (int k = 0; k < 4; ++k) {
                int n = nbase + k;
                int beg = row_start[n], end = row_start[n + 1];
                float ax = 0.0f, ay = 0.0f;
                int i = beg;
                for (; i + 8 <= end; i += 8) {
                    int s0 = __builtin_nontemporal_load(&csr_src[i + g]);
                    int s1 = __builtin_nontemporal_load(&csr_src[i + 4 + g]);
                    float c0 = dsq[s0], c1 = dsq[s1];
                    unsigned int p0 = *(const unsigned int*)&srcS[(size_t)s0 * 32 + fl * 2];
                    unsigned int p1 = *(const unsigned int*)&srcS[(size_t)s1 * 32 + fl * 2];
                    ax += c0 * bf2f(p0 & 0xffffu) + c1 * bf2f(p1 & 0xffffu);
                    ay += c0 * bf2f(p0 >> 16) + c1 * bf2f(p1 >> 16);
                }
                for (; i < end; i += 4) {
                    int idx = i + g;
                    bool act = idx < end;
                    int s0 = act ? __builtin_nontemporal_load(&csr_src[idx]) : 0;
                    float c0 = act ? dsq[s0] : 0.0f;
                    unsigned int p0 = *(const unsigned int*)&srcS[(size_t)s0 * 32 + fl * 2];
                    ax += c0 * bf2f(p0 & 0xffffu);
                    ay += c0 * bf2f(p0 >> 16);
                }
                ax += __shfl_down(ax, 32); ay += __shfl_down(ay, 32);
                ax += __shfl_down(ax, 16); ay += __shfl_down(ay, 16);
                if (lane < 16) {
                    float a = am * dsq[n];
                    unsigned int pu = *(const unsigned int*)&srcS[(size_t)n * 32 + fl * 2];
                    float rx = a * ax + bcoef * bf2f(pu & 0xffffu);
                    float ry = a * ay + bcoef * bf2f(pu >> 16);
                    if (ppS) {
                        unsigned int qu = __builtin_nontemporal_load(
                            (const unsigned int*)&ppS[(size_t)n * 32 + fl * 2]);
                        rx -= bf2f(qu & 0xffffu);
                        ry -= bf2f(qu >> 16);
                    }
                    unsigned int packed = (unsigned int)f2bf(rx) | ((unsigned int)f2bf(ry) << 16);
                    __builtin_nontemporal_store(packed,
                        (unsigned int*)&outS[(size_t)n * 32 + fl * 2]);
                }
            }
        }
    }
}

// eigen-MLP: 64 blocks (one per eigenvalue), 128 threads
__global__ __launch_bounds__(128) void k_ef2(const float* __restrict__ evals,
                                             const float* __restrict__ ew0,
                                             const float* __restrict__ eb0,
                                             const float* __restrict__ ew1,
                                             const float* __restrict__ eb1,
                                             const float* __restrict__ ew2,
                                             const float* __restrict__ eb2,
                                             float* __restrict__ ef) {
    __shared__ float z0[HDIM];
    __shared__ float red[HDIM];
    int i = blockIdx.x, j = threadIdx.x;
    float ev = evals[i];
    z0[j] = fmaxf(0.0f, ev * ew0[j] + eb0[j]);
    __syncthreads();
    float s0 = 0.f, s1 = 0.f, s2 = 0.f, s3 = 0.f;
    for (int h = 0; h < HDIM; h += 4) {
        s0 += z0[h]     * ew1[(h) * HDIM + j];
        s1 += z0[h + 1] * ew1[(h + 1) * HDIM + j];
        s2 += z0[h + 2] * ew1[(h + 2) * HDIM + j];
        s3 += z0[h + 3] * ew1[(h + 3) * HDIM + j];
    }
    float z1 = fmaxf(0.0f, eb1[j] + s0 + s1 + s2 + s3);
    red[j] = z1 * ew2[j];
    __syncthreads();
    for (int off = 64; off > 0; off >>= 1) {
        if (j < off) red[j] += red[j + off];
        __syncthreads();
    }
    if (j == 0) ef[i] = red[0] + eb2[0];
}

// hs partial: block b handles 96 nodes; partial C[64][128] -> partials[b]
__global__ __launch_bounds__(256) void k_hs_partial2(const float* __restrict__ evecs,
                                                     const float* __restrict__ feat,
                                                     float* __restrict__ partials) {
    __shared__ float sEv[32 * NEIG];    // 8 KB
    __shared__ float sFt[32 * IN_F];    // 16 KB
    int t = threadIdx.x;
    int e0 = (t >> 5) * 8;
    int f0 = (t & 31) * 4;
    float acc[8][4];
#pragma unroll
    for (int r = 0; r < 8; ++r)
#pragma unroll
        for (int c = 0; c < 4; ++c) acc[r][c] = 0.0f;

    int n0 = blockIdx.x * HSP_NODES;
    for (int ch = 0; ch < HSP_NODES; ch += 32) {
        int base = n0 + ch;
        {
            int r = t >> 3, c = (t & 7) * 8;
            int n = base + r;
            float4 a, b;
            if (n < N_NODES) {
                a = *(const float4*)&evecs[(size_t)n * NEIG + c];
                b = *(const float4*)&evecs[(size_t)n * NEIG + c + 4];
            } else {
                a = make_float4(0, 0, 0, 0); b = a;
            }
            *(float4*)&sEv[r * NEIG + c] = a;
            *(float4*)&sEv[r * NEIG + c + 4] = b;
        }
        {
            int r = t >> 3, c = (t & 7) * 16;
            int n = base + r;
#pragma unroll
            for (int q = 0; q < 4; ++q) {
                float4 v = (n < N_NODES) ? *(const float4*)&feat[(size_t)n * IN_F + c + q * 4]
                                         : make_float4(0, 0, 0, 0);
                *(float4*)&sFt[r * IN_F + c + q * 4] = v;
            }
        }
        __syncthreads();
#pragma unroll 2
        for (int i = 0; i < 32; ++i) {
            float4 ev0 = *(float4*)&sEv[i * NEIG + e0];
            float4 ev1 = *(float4*)&sEv[i * NEIG + e0 + 4];
            float4 fv  = *(float4*)&sFt[i * IN_F + f0];
            float evv[8] = {ev0.x, ev0.y, ev0.z, ev0.w, ev1.x, ev1.y, ev1.z, ev1.w};
#pragma unroll
            for (int r = 0; r < 8; ++r) {
                acc[r][0] += evv[r] * fv.x;
                acc[r][1] += evv[r] * fv.y;
                acc[r][2] += evv[r] * fv.z;
                acc[r][3] += evv[r] * fv.w;
            }
        }
        __syncthreads();
    }
    float* p = &partials[(size_t)blockIdx.x * (NEIG * IN_F)];
#pragma unroll
    for (int r = 0; r < 8; ++r)
        *(float4*)&p[(e0 + r) * IN_F + f0] = make_float4(acc[r][0], acc[r][1], acc[r][2], acc[r][3]);
}

// split reduce: 32 element-groups x 16 j-chunks; atomicAdd into pre-zeroed hs_small
__global__ __launch_bounds__(256) void k_hs_reduce(const float* __restrict__ partials,
                                                   float* __restrict__ hs_small) {
    int grp   = blockIdx.x & 31;
    int chunk = blockIdx.x >> 5;
    int idx = grp * 256 + threadIdx.x;
    int j0 = chunk * RED_CHUNK;
    int j1 = min(j0 + RED_CHUNK, HSP_BLOCKS);
    float s = 0.0f;
    for (int j = j0; j < j1; ++j) s += partials[(size_t)j * (NEIG * IN_F) + idx];
    atomicAdd(&hs_small[idx], s);
}

// hs chunks 16-19 of XS: XS[16+f/32][n][f%32] = bf16(sum_e evecs[n,e]*ef[e]*hs_small[e,f])
__global__ __launch_bounds__(256) void k_hs_apply2(unsigned short* __restrict__ XS,
                                                   const float* __restrict__ evecs,
                                                   const float* __restrict__ hs_small,
                                                   const float* __restrict__ ef) {
    __shared__ float sShs[NEIG * HDIM];
    __shared__ float sEv[32 * NEIG];
    int t = threadIdx.x;
    int n0 = blockIdx.x * 32;
    {
        float efv = ef[t >> 2];
        int pbase = t * 32;
#pragma unroll
        for (int q = 0; q < 8; ++q) {
            float4 v = *(const float4*)&hs_small[pbase + q * 4];
            v.x *= efv; v.y *= efv; v.z *= efv; v.w *= efv;
            *(float4*)&sShs[pbase + q * 4] = v;
        }
    }
    {
        int r = t >> 3, c = (t & 7) * 8;
        int n = n0 + r;
        float4 a, b;
        if (n < N_NODES) {
            a = *(const float4*)&evecs[(size_t)n * NEIG + c];
            b = *(const float4*)&evecs[(size_t)n * NEIG + c + 4];
        } else {
            a = make_float4(0, 0, 0, 0); b = a;
        }
        *(float4*)&sEv[r * NEIG + c] = a;
        *(float4*)&sEv[r * NEIG + c + 4] = b;
    }
    __syncthreads();
    int nb = (t >> 5) * 4;
    int f0 = (t & 31) * 4;
    float acc[4][4];
#pragma unroll
    for (int q = 0; q < 4; ++q)
#pragma unroll
        for (int c = 0; c < 4; ++c) acc[q][c] = 0.0f;
    for (int e = 0; e < NEIG; ++e) {
        float4 sv = *(float4*)&sShs[e * HDIM + f0];
#pragma unroll
        for (int q = 0; q < 4; ++q) {
            float evv = sEv[(nb + q) * NEIG + e];
            acc[q][0] += evv * sv.x;
            acc[q][1] += evv * sv.y;
            acc[q][2] += evv * sv.z;
            acc[q][3] += evv * sv.w;
        }
    }
    unsigned short* outc = XS + (size_t)(16 + (f0 >> 5)) * N32;
    int within = f0 & 31;
#pragma unroll
    for (int q = 0; q < 4; ++q) {
        int n = n0 + nb + q;
        if (n < N_NODES) {
            ushort4 o;
            o.x = f2bf(acc[q][0]); o.y = f2bf(acc[q][1]);
            o.z = f2bf(acc[q][2]); o.w = f2bf(acc[q][3]);
            *(ushort4*)&outc[(size_t)n * 32 + within] = o;
        }
    }
}

// MFMA bf16 GEMM reading XS chunks (chunk = k-tile), fused BN column-stats.
__global__ __launch_bounds__(256) void k_gemm(const unsigned short* __restrict__ XS,
                                              const unsigned short* __restrict__ Wt,
                                              const float* __restrict__ bias,
                                              float* __restrict__ out,
                                              float* __restrict__ colsum,
                                              float* __restrict__ colsq) {
    __shared__ unsigned short sA[128 * 32];
    __shared__ unsigned short sB[128 * 32];
    __shared__ float cs[4][OUT_F];
    __shared__ float cq[4][OUT_F];
    int tid = threadIdx.x;
    int wave = tid >> 6, lane = tid & 63;
    int quad = lane >> 4, m16 = lane & 15;
    int row0 = blockIdx.x * 128;

    floatx4 acc[2][8];
#pragma unroll
    for (int mt = 0; mt < 2; ++mt)
#pragma unroll
        for (int nt = 0; nt < 8; ++nt) acc[mt][nt] = (floatx4)(0.0f);

    int r  = tid >> 2;
    int c8 = (tid & 3) * 8;
    int gr0 = min(row0 + r, N_NODES - 1);
    int gr1 = min(row0 + r + 64, N_NODES - 1);

    for (int k0 = 0; k0 < 640; k0 += 32) {
        const unsigned short* base = XS + (size_t)(k0 >> 5) * N32;
        *(uint4*)&sA[r * 32 + c8]        = *(const uint4*)&base[(size_t)gr0 * 32 + c8];
        *(uint4*)&sA[(r + 64) * 32 + c8] = *(const uint4*)&base[(size_t)gr1 * 32 + c8];
        *(uint4*)&sB[r * 32 + c8]        = *(const uint4*)&Wt[r * 640 + k0 + c8];
        *(uint4*)&sB[(r + 64) * 32 + c8] = *(const uint4*)&Wt[(r + 64) * 640 + k0 + c8];
        __syncthreads();
        short8 a0 = *(short8*)&sA[(wave * 32 + m16) * 32 + quad * 8];
        short8 a1 = *(short8*)&sA[(wave * 32 + 16 + m16) * 32 + quad * 8];
#pragma unroll
        for (int nt = 0; nt < 8; ++nt) {
            short8 b = *(short8*)&sB[(nt * 16 + m16) * 32 + quad * 8];
            acc[0][nt] = __builtin_amdgcn_mfma_f32_16x16x32_bf16(a0, b, acc[0][nt], 0, 0, 0);
            acc[1][nt] = __builtin_amdgcn_mfma_f32_16x16x32_bf16(a1, b, acc[1][nt], 0, 0, 0);
        }
        __syncthreads();
    }
#pragma unroll
    for (int nt = 0; nt < 8; ++nt) {
        int col = nt * 16 + m16;
        float bb = bias[col];
        float sv = 0.0f, sq = 0.0f;
#pragma unroll
        for (int mt = 0; mt < 2; ++mt) {
            int rbase = row0 + wave * 32 + mt * 16 + quad * 4;
#pragma unroll
            for (int reg = 0; reg < 4; ++reg) {
                int row = rbase + reg;
                if (row < N_NODES) {
                    float w = acc[mt][nt][reg] + bb;
                    out[(size_t)row * OUT_F + col] = w;
                    sv += w;
                    sq += w * w;
                }
            }
        }
        sv += __shfl_down(sv, 32); sq += __shfl_down(sq, 32);
        sv += __shfl_down(sv, 16); sq += __shfl_down(sq, 16);
        if (lane < 16) { cs[wave][col] = sv; cq[wave][col] = sq; }
    }
    __syncthreads();
    if (tid < OUT_F) {
        float s = cs[0][tid] + cs[1][tid] + cs[2][tid] + cs[3][tid];
        float q = cq[0][tid] + cq[1][tid] + cq[2][tid] + cq[3][tid];
        atomicAdd(&colsum[tid], s);
        atomicAdd(&colsq[tid], q);
    }
}

__global__ void k_bn_apply(float* __restrict__ out, const float* __restrict__ colsum,
                           const float* __restrict__ colsq, const float* __restrict__ gamma,
                           const float* __restrict__ beta) {
    int t = blockIdx.x * 256 + threadIdx.x;
    int n = t >> 5, c = t & 31;
    float4 v = *(float4*)&out[n * OUT_F + c * 4];
    float4 s = *(const float4*)&colsum[c * 4];
    float4 q = *(const float4*)&colsq[c * 4];
    float4 g = *(const float4*)&gamma[c * 4];
    float4 b = *(const float4*)&beta[c * 4];
    const float invN = 1.0f / (float)N_NODES;
    float mux = s.x * invN, muy = s.y * invN, muz = s.z * invN, muw = s.w * invN;
    float ix = rsqrtf(q.x * invN - mux * mux + BN_EPSF);
    float iy = rsqrtf(q.y * invN - muy * muy + BN_EPSF);
    float iz = rsqrtf(q.z * invN - muz * muz + BN_EPSF);
    float iw = rsqrtf(q.w * invN - muw * muw + BN_EPSF);
    v.x = fmaxf(0.0f, (v.x - mux) * ix * g.x + b.x);
    v.y = fmaxf(0.0f, (v.y - muy) * iy * g.y + b.y);
    v.z = fmaxf(0.0f, (v.z - muz) * iz * g.z + b.z);
    v.w = fmaxf(0.0f, (v.w - muw) * iw * g.w + b.w);
    *(float4*)&out[n * OUT_F + c * 4] = v;
}

extern "C" void kernel_launch(void* const* d_in, const int* in_sizes, int n_in,
                              void* d_out, int out_size, void* d_ws, size_t ws_size,
                              hipStream_t stream) {
    const float* feature    = (const float*)d_in[0];
    const float* lin_w      = (const float*)d_in[1];
    const float* lin_b      = (const float*)d_in[2];
    const float* ew0        = (const float*)d_in[3];
    const float* eb0        = (const float*)d_in[4];
    const float* ew1        = (const float*)d_in[5];
    const float* eb1        = (const float*)d_in[6];
    const float* ew2        = (const float*)d_in[7];
    const float* eb2        = (const float*)d_in[8];
    const float* bn_gamma   = (const float*)d_in[9];
    const float* bn_beta    = (const float*)d_in[10];
    const float* lambda_max = (const float*)d_in[11];
    const float* evecs      = (const float*)d_in[12];
    const float* evals      = (const float*)d_in[13];
    const int*   edge_src   = (const int*)d_in[14];
    const int*   edge_dst   = (const int*)d_in[15];

    float* out = (float*)d_out;
    float* ws  = (float*)d_ws;
    unsigned short* XS = (unsigned short*)(ws + OFF_XS);
    float* partials = ws + OFF_PART;
    unsigned short* Wt = (unsigned short*)(ws + OFF_WT);
    float* dsq      = ws + OFF_DSQRT;
    float* hs_small = ws + OFF_HS;
    float* ef       = ws + OFF_EF;
    float* colsum   = ws + OFF_COLSUM;
    float* colsq    = ws + OFF_COLSQ;
    int*   cursors  = (int*)(ws + OFF_CUR);
    int*   deg      = (int*)(ws + OFF_DEG);
    int*   row_start= (int*)(ws + OFF_ROWSTART);
    int*   csr_src  = (int*)(ws + OFF_CSR);
    int*   bsum     = (int*)(ws + OFF_BSUM);
    int*   rank     = (int*)(ws + OFF_RANK);

    // ---- prep (feat->X0 slice-major bf16, Wt, zero deg/stats/cursors) + CSR ----
    k_prep<<<3674, 256, 0, stream>>>(feature, lin_w, XS, Wt, deg, ws + OFF_HS);
    k_rank<<<(N_EDGES + 255) / 256, 256, 0, stream>>>(deg, edge_dst, rank);
    k_scan1<<<SCAN_BLK, 1024, 0, stream>>>(deg, row_start, bsum);
    k_scan2<<<1, 64, 0, stream>>>(bsum);
    k_scan3<<<SCAN_BLK, 1024, 0, stream>>>(deg, row_start, bsum, dsq);
    k_csr<<<(N_EDGES + 255) / 256, 256, 0, stream>>>(edge_src, edge_dst, rank, row_start, csr_src);

    // ---- Chebyshev recurrence: XCD-pinned slice-resident gathers ----
    // X1 = f(X0): src/prev chunks 0-3, out 4-7
    k_gather<<<GATHER_BLOCKS, 256, 0, stream>>>(row_start, csr_src, dsq, XS, lambda_max,
                                                1, 0, -1, 4, cursors + 0);
    // X2 = f(X1, pp=X0): src 4-7, pp 0-3, out 8-11
    k_gather<<<GATHER_BLOCKS, 256, 0, stream>>>(row_start, csr_src, dsq, XS, lambda_max,
                                                0, 4, 0, 8, cursors + 4);
    // X3 = f(X2, pp=X1): src 8-11, pp 4-7, out 12-15
    k_gather<<<GATHER_BLOCKS, 256, 0, stream>>>(row_start, csr_src, dsq, XS, lambda_max,
                                                0, 8, 4, 12, cursors + 8);

    // ---- eigen block ----
    k_ef2<<<NEIG, 128, 0, stream>>>(evals, ew0, eb0, ew1, eb1, ew2, eb2, ef);
    k_hs_partial2<<<HSP_BLOCKS, 256, 0, stream>>>(evecs, feature, partials);
    k_hs_reduce<<<32 * RED_SPLIT, 256, 0, stream>>>(partials, hs_small);
    k_hs_apply2<<<(N_NODES + 31) / 32, 256, 0, stream>>>(XS, evecs, hs_small, ef);

    // ---- MFMA linear (+BN stats) + BN apply ----
    k_gemm<<<(N_NODES + 127) / 128, 256, 0, stream>>>(XS, Wt, lin_b, out, colsum, colsq);
    k_bn_apply<<<(N_NODES * 32) / 256, 256, 0, stream>>>(out, colsum, colsq, bn_gamma, bn_beta);
}

// Round 12
// 367.384 us; speedup vs baseline: 2.8091x; 2.8091x over previous
//
#include <hip/hip_runtime.h>

#define N_NODES 50000
#define N_EDGES 800000
#define IN_F    128
#define OUT_F   128
#define NEIG    64
#define HDIM    128
#define BN_EPSF 1e-5f
#define XB_ROWS 50048            // 50000 padded to 128
#define XB_COLS 640
#define SCAN_BLK 49              // ceil(50000/1024)
#define HSP_BLOCKS 521           // 521*96 >= 50000
#define HSP_NODES 96
#define RED_CHUNK 33             // ceil(521/16)
#define RED_SPLIT 16

typedef __attribute__((ext_vector_type(8))) short short8;
typedef __attribute__((ext_vector_type(4))) float floatx4;

// ---- workspace layout (in 4-byte units) ----
#define OFF_XB      0                                   // ushort[50048*640] -> 16,015,360 floats
#define OFF_X1F     (XB_ROWS * XB_COLS / 2)             // 16,015,360 (hs partials region)
#define OFF_X2F     (OFF_X1F + N_NODES * IN_F)          // 22,415,360 (unused)
#define OFF_WT      (OFF_X2F + N_NODES * IN_F)          // 28,815,360 (ushort[640*128] = 40,960 floats)
#define OFF_DSQRT   (OFF_WT + 40960)                    // 28,856,320
#define OFF_HS      (OFF_DSQRT + N_NODES)
#define OFF_EF      (OFF_HS + NEIG * OUT_F)
#define OFF_COLSUM  (OFF_EF + NEIG)
#define OFF_COLSQ   (OFF_COLSUM + OUT_F)
#define OFF_DEG     (OFF_COLSQ + OUT_F)
#define OFF_ROWSTART (OFF_DEG + N_NODES)
#define OFF_CSR     (OFF_ROWSTART + N_NODES + 1)
#define OFF_BSUM    (OFF_CSR + N_EDGES)                 // 64 ints
#define OFF_RANK    (OFF_BSUM + 64)                     // E ints
// end ~= 30.7M * 4B ~= 122.9 MB (< 128.3 MB proven in R0)

static __device__ inline unsigned short f2bf(float f) {
    union { float f; unsigned int u; } v; v.f = f;
    unsigned int r = (v.u + 0x7FFFu + ((v.u >> 16) & 1u)) >> 16;
    return (unsigned short)r;
}
static __device__ inline float bf2f(unsigned int u16) {
    union { unsigned int u; float f; } v; v.u = u16 << 16;
    return v.f;
}

// merged: feat2bf (blocks 0..3124) | wt (3125..3444) | zero deg+stats (3445..3673)
__global__ __launch_bounds__(256) void k_prep(const float* __restrict__ feat,
                                              const float* __restrict__ W,
                                              unsigned short* __restrict__ Xb,
                                              unsigned short* __restrict__ Wt,
                                              int* __restrict__ deg,
                                              float* __restrict__ small) {
    int b = blockIdx.x;
    if (b < 3125) {
        int t = b * 256 + threadIdx.x;           // [0, 800000)
        int n = t >> 4, c8 = (t & 15) * 8;
        float4 a = *(const float4*)&feat[n * IN_F + c8];
        float4 bb = *(const float4*)&feat[n * IN_F + c8 + 4];
        ushort4 o0, o1;
        o0.x = f2bf(a.x); o0.y = f2bf(a.y); o0.z = f2bf(a.z); o0.w = f2bf(a.w);
        o1.x = f2bf(bb.x); o1.y = f2bf(bb.y); o1.z = f2bf(bb.z); o1.w = f2bf(bb.w);
        *(ushort4*)&Xb[(size_t)n * XB_COLS + c8]     = o0;
        *(ushort4*)&Xb[(size_t)n * XB_COLS + c8 + 4] = o1;
    } else if (b < 3445) {
        int t = (b - 3125) * 256 + threadIdx.x;  // [0, 81920)
        int k = t >> 7, n = t & 127;
        Wt[n * 640 + k] = f2bf(W[k * 128 + n]);
    } else {
        int i = (b - 3445) * 256 + threadIdx.x;
        if (i < N_NODES) deg[i] = 0;
        if (i < NEIG * OUT_F + NEIG + 2 * OUT_F) small[i] = 0.0f;
    }
}

// per-edge rank within its dst bucket (atomic); deg = counts afterwards
__global__ void k_rank(int* __restrict__ deg, const int* __restrict__ dst,
                       int* __restrict__ rank) {
    int e = blockIdx.x * 256 + threadIdx.x;
    if (e < N_EDGES) rank[e] = atomicAdd(&deg[dst[e]], 1);
}

// ---- 3-stage parallel scan ----
__global__ __launch_bounds__(1024) void k_scan1(const int* __restrict__ deg,
                                                int* __restrict__ row_start,
                                                int* __restrict__ bsum) {
    __shared__ int sd[1024];
    int i = blockIdx.x * 1024 + threadIdx.x;
    int v = (i < N_NODES) ? deg[i] : 0;
    sd[threadIdx.x] = v;
    __syncthreads();
    for (int off = 1; off < 1024; off <<= 1) {
        int t = (threadIdx.x >= off) ? sd[threadIdx.x - off] : 0;
        __syncthreads();
        sd[threadIdx.x] += t;
        __syncthreads();
    }
    if (i < N_NODES) row_start[i] = sd[threadIdx.x] - v;
    if (threadIdx.x == 1023) bsum[blockIdx.x] = sd[1023];
}

__global__ void k_scan2(int* __restrict__ bsum) {
    int t = threadIdx.x;
    int orig = (t < SCAN_BLK) ? bsum[t] : 0;
    int v = orig;
    for (int off = 1; off < 64; off <<= 1) {
        int u = __shfl_up(v, off);
        if (t >= off) v += u;
    }
    if (t < SCAN_BLK) bsum[t] = v - orig;
}

__global__ __launch_bounds__(1024) void k_scan3(const int* __restrict__ deg,
                                                int* __restrict__ row_start,
                                                const int* __restrict__ bsum,
                                                float* __restrict__ dsq) {
    int i = blockIdx.x * 1024 + threadIdx.x;
    if (i < N_NODES) {
        int r = row_start[i] + bsum[blockIdx.x];
        row_start[i] = r;
        dsq[i] = rsqrtf((float)max(deg[i], 1));
    }
    if (i == 0) row_start[N_NODES] = N_EDGES;
}

// scatter csr entries, no atomics (rank precomputed)
__global__ void k_csr(const int* __restrict__ src, const int* __restrict__ dst,
                      const int* __restrict__ rank, const int* __restrict__ row_start,
                      int* __restrict__ csr_src) {
    int e = blockIdx.x * 256 + threadIdx.x;
    if (e < N_EDGES) csr_src[row_start[dst[e]] + rank[e]] = src[e];
}

// One wave per node, all-bf16 state. 16x/8x/4x unrolled edge loop: up to 16
// independent 256 B row-loads in flight per wave (the gather is MLP-bound —
// R11 showed traffic reduction without MLP regresses 6x).
__global__ __launch_bounds__(256) void k_gather(const int* __restrict__ row_start,
                                                const int* __restrict__ csr_src,
                                                const float* __restrict__ dsq,
                                                const unsigned short* __restrict__ srcb,
                                                const unsigned short* __restrict__ prevb,
                                                const unsigned short* __restrict__ ppb,
                                                unsigned short* __restrict__ outb,
                                                const float* __restrict__ lm, int first) {
    int n = (blockIdx.x * 256 + threadIdx.x) >> 6;
    int lane = threadIdx.x & 63;
    if (n >= N_NODES) return;
    float rn = 2.0f / lm[0];
    float ax = 0.0f, ay = 0.0f;
    int beg = row_start[n], end = row_start[n + 1];
    int i = beg;
    for (; i + 16 <= end; i += 16) {
        int s[16]; float c[16]; unsigned int p[16];
#pragma unroll
        for (int j = 0; j < 16; ++j) s[j] = __builtin_amdgcn_readfirstlane(csr_src[i + j]);
#pragma unroll
        for (int j = 0; j < 16; ++j) c[j] = dsq[s[j]];
#pragma unroll
        for (int j = 0; j < 16; ++j)
            p[j] = *(const unsigned int*)&srcb[(size_t)s[j] * XB_COLS + lane * 2];
#pragma unroll
        for (int j = 0; j < 16; ++j) {
            ax += c[j] * bf2f(p[j] & 0xffffu);
            ay += c[j] * bf2f(p[j] >> 16);
        }
    }
    for (; i + 8 <= end; i += 8) {
        int s[8]; float c[8]; unsigned int p[8];
#pragma unroll
        for (int j = 0; j < 8; ++j) s[j] = __builtin_amdgcn_readfirstlane(csr_src[i + j]);
#pragma unroll
        for (int j = 0; j < 8; ++j) c[j] = dsq[s[j]];
#pragma unroll
        for (int j = 0; j < 8; ++j)
            p[j] = *(const unsigned int*)&srcb[(size_t)s[j] * XB_COLS + lane * 2];
#pragma unroll
        for (int j = 0; j < 8; ++j) {
            ax += c[j] * bf2f(p[j] & 0xffffu);
            ay += c[j] * bf2f(p[j] >> 16);
        }
    }
    for (; i + 4 <= end; i += 4) {
        int s[4]; float c[4]; unsigned int p[4];
#pragma unroll
        for (int j = 0; j < 4; ++j) s[j] = __builtin_amdgcn_readfirstlane(csr_src[i + j]);
#pragma unroll
        for (int j = 0; j < 4; ++j) c[j] = dsq[s[j]];
#pragma unroll
        for (int j = 0; j < 4; ++j)
            p[j] = *(const unsigned int*)&srcb[(size_t)s[j] * XB_COLS + lane * 2];
#pragma unroll
        for (int j = 0; j < 4; ++j) {
            ax += c[j] * bf2f(p[j] & 0xffffu);
            ay += c[j] * bf2f(p[j] >> 16);
        }
    }
    for (; i < end; ++i) {
        int s = __builtin_amdgcn_readfirstlane(csr_src[i]);
        float sc = dsq[s];
        unsigned int pv = *(const unsigned int*)&srcb[(size_t)s * XB_COLS + lane * 2];
        ax += sc * bf2f(pv & 0xffffu);
        ay += sc * bf2f(pv >> 16);
    }
    float ds = dsq[n];
    float a = (first ? -rn : -2.0f * rn) * ds;
    float b = first ? (rn - 1.0f) : 2.0f * (rn - 1.0f);
    unsigned int pu = *(const unsigned int*)&prevb[(size_t)n * XB_COLS + lane * 2];
    float rx = a * ax + b * bf2f(pu & 0xffffu);
    float ry = a * ay + b * bf2f(pu >> 16);
    if (ppb) {
        unsigned int qu = *(const unsigned int*)&ppb[(size_t)n * XB_COLS + lane * 2];
        rx -= bf2f(qu & 0xffffu);
        ry -= bf2f(qu >> 16);
    }
    unsigned int packed = (unsigned int)f2bf(rx) | ((unsigned int)f2bf(ry) << 16);
    *(unsigned int*)&outb[(size_t)n * XB_COLS + lane * 2] = packed;
}

// eigen-MLP: 64 blocks (one per eigenvalue), 128 threads
__global__ __launch_bounds__(128) void k_ef2(const float* __restrict__ evals,
                                             const float* __restrict__ ew0,
                                             const float* __restrict__ eb0,
                                             const float* __restrict__ ew1,
                                             const float* __restrict__ eb1,
                                             const float* __restrict__ ew2,
                                             const float* __restrict__ eb2,
                                             float* __restrict__ ef) {
    __shared__ float z0[HDIM];
    __shared__ float red[HDIM];
    int i = blockIdx.x, j = threadIdx.x;
    float ev = evals[i];
    z0[j] = fmaxf(0.0f, ev * ew0[j] + eb0[j]);
    __syncthreads();
    float s0 = 0.f, s1 = 0.f, s2 = 0.f, s3 = 0.f;
    for (int h = 0; h < HDIM; h += 4) {
        s0 += z0[h]     * ew1[(h) * HDIM + j];
        s1 += z0[h + 1] * ew1[(h + 1) * HDIM + j];
        s2 += z0[h + 2] * ew1[(h + 2) * HDIM + j];
        s3 += z0[h + 3] * ew1[(h + 3) * HDIM + j];
    }
    float z1 = fmaxf(0.0f, eb1[j] + s0 + s1 + s2 + s3);
    red[j] = z1 * ew2[j];
    __syncthreads();
    for (int off = 64; off > 0; off >>= 1) {
        if (j < off) red[j] += red[j + off];
        __syncthreads();
    }
    if (j == 0) ef[i] = red[0] + eb2[0];
}

// hs partial: block b handles 96 nodes; partial C[64][128] -> partials[b]
__global__ __launch_bounds__(256) void k_hs_partial2(const float* __restrict__ evecs,
                                                     const float* __restrict__ feat,
                                                     float* __restrict__ partials) {
    __shared__ float sEv[32 * NEIG];    // 8 KB
    __shared__ float sFt[32 * IN_F];    // 16 KB
    int t = threadIdx.x;
    int e0 = (t >> 5) * 8;
    int f0 = (t & 31) * 4;
    float acc[8][4];
#pragma unroll
    for (int r = 0; r < 8; ++r)
#pragma unroll
        for (int c = 0; c < 4; ++c) acc[r][c] = 0.0f;

    int n0 = blockIdx.x * HSP_NODES;
    for (int ch = 0; ch < HSP_NODES; ch += 32) {
        int base = n0 + ch;
        {
            int r = t >> 3, c = (t & 7) * 8;
            int n = base + r;
            float4 a, b;
            if (n < N_NODES) {
                a = *(const float4*)&evecs[(size_t)n * NEIG + c];
                b = *(const float4*)&evecs[(size_t)n * NEIG + c + 4];
            } else {
                a = make_float4(0, 0, 0, 0); b = a;
            }
            *(float4*)&sEv[r * NEIG + c] = a;
            *(float4*)&sEv[r * NEIG + c + 4] = b;
        }
        {
            int r = t >> 3, c = (t & 7) * 16;
            int n = base + r;
#pragma unroll
            for (int q = 0; q < 4; ++q) {
                float4 v = (n < N_NODES) ? *(const float4*)&feat[(size_t)n * IN_F + c + q * 4]
                                         : make_float4(0, 0, 0, 0);
                *(float4*)&sFt[r * IN_F + c + q * 4] = v;
            }
        }
        __syncthreads();
#pragma unroll 2
        for (int i = 0; i < 32; ++i) {
            float4 ev0 = *(float4*)&sEv[i * NEIG + e0];
            float4 ev1 = *(float4*)&sEv[i * NEIG + e0 + 4];
            float4 fv  = *(float4*)&sFt[i * IN_F + f0];
            float evv[8] = {ev0.x, ev0.y, ev0.z, ev0.w, ev1.x, ev1.y, ev1.z, ev1.w};
#pragma unroll
            for (int r = 0; r < 8; ++r) {
                acc[r][0] += evv[r] * fv.x;
                acc[r][1] += evv[r] * fv.y;
                acc[r][2] += evv[r] * fv.z;
                acc[r][3] += evv[r] * fv.w;
            }
        }
        __syncthreads();
    }
    float* p = &partials[(size_t)blockIdx.x * (NEIG * IN_F)];
#pragma unroll
    for (int r = 0; r < 8; ++r)
        *(float4*)&p[(e0 + r) * IN_F + f0] = make_float4(acc[r][0], acc[r][1], acc[r][2], acc[r][3]);
}

// split reduce: 32 element-groups x 16 j-chunks; atomicAdd into pre-zeroed hs_small
__global__ __launch_bounds__(256) void k_hs_reduce(const float* __restrict__ partials,
                                                   float* __restrict__ hs_small) {
    int grp   = blockIdx.x & 31;
    int chunk = blockIdx.x >> 5;
    int idx = grp * 256 + threadIdx.x;
    int j0 = chunk * RED_CHUNK;
    int j1 = min(j0 + RED_CHUNK, HSP_BLOCKS);
    float s = 0.0f;
    for (int j = j0; j < j1; ++j) s += partials[(size_t)j * (NEIG * IN_F) + idx];
    atomicAdd(&hs_small[idx], s);
}

// Xb[n, 512+f] = bf16( sum_e evecs[n,e] * ef[e] * hs_small[e,f] ); 32 nodes/block
__global__ __launch_bounds__(256) void k_hs_apply2(unsigned short* __restrict__ Xb,
                                                   const float* __restrict__ evecs,
                                                   const float* __restrict__ hs_small,
                                                   const float* __restrict__ ef) {
    __shared__ float sShs[NEIG * HDIM];
    __shared__ float sEv[32 * NEIG];
    int t = threadIdx.x;
    int n0 = blockIdx.x * 32;
    {
        float efv = ef[t >> 2];
        int pbase = t * 32;
#pragma unroll
        for (int q = 0; q < 8; ++q) {
            float4 v = *(const float4*)&hs_small[pbase + q * 4];
            v.x *= efv; v.y *= efv; v.z *= efv; v.w *= efv;
            *(float4*)&sShs[pbase + q * 4] = v;
        }
    }
    {
        int r = t >> 3, c = (t & 7) * 8;
        int n = n0 + r;
        float4 a, b;
        if (n < N_NODES) {
            a = *(const float4*)&evecs[(size_t)n * NEIG + c];
            b = *(const float4*)&evecs[(size_t)n * NEIG + c + 4];
        } else {
            a = make_float4(0, 0, 0, 0); b = a;
        }
        *(float4*)&sEv[r * NEIG + c] = a;
        *(float4*)&sEv[r * NEIG + c + 4] = b;
    }
    __syncthreads();
    int nb = (t >> 5) * 4;
    int f0 = (t & 31) * 4;
    float acc[4][4];
#pragma unroll
    for (int q = 0; q < 4; ++q)
#pragma unroll
        for (int c = 0; c < 4; ++c) acc[q][c] = 0.0f;
    for (int e = 0; e < NEIG; ++e) {
        float4 sv = *(float4*)&sShs[e * HDIM + f0];
#pragma unroll
        for (int q = 0; q < 4; ++q) {
            float evv = sEv[(nb + q) * NEIG + e];
            acc[q][0] += evv * sv.x;
            acc[q][1] += evv * sv.y;
            acc[q][2] += evv * sv.z;
            acc[q][3] += evv * sv.w;
        }
    }
#pragma unroll
    for (int q = 0; q < 4; ++q) {
        int n = n0 + nb + q;
        if (n < N_NODES) {
            ushort4 o;
            o.x = f2bf(acc[q][0]); o.y = f2bf(acc[q][1]);
            o.z = f2bf(acc[q][2]); o.w = f2bf(acc[q][3]);
            *(ushort4*)&Xb[(size_t)n * XB_COLS + 4 * IN_F + f0] = o;
        }
    }
}

// MFMA bf16 GEMM with fused BN column-stats (shfl + per-wave LDS, no LDS atomics)
__global__ __launch_bounds__(256) void k_gemm(const unsigned short* __restrict__ Xb,
                                              const unsigned short* __restrict__ Wt,
                                              const float* __restrict__ bias,
                                              float* __restrict__ out,
                                              float* __restrict__ colsum,
                                              float* __restrict__ colsq) {
    __shared__ unsigned short sA[128 * 32];
    __shared__ unsigned short sB[128 * 32];
    __shared__ float cs[4][OUT_F];
    __shared__ float cq[4][OUT_F];
    int tid = threadIdx.x;
    int wave = tid >> 6, lane = tid & 63;
    int quad = lane >> 4, m16 = lane & 15;
    int row0 = blockIdx.x * 128;

    floatx4 acc[2][8];
#pragma unroll
    for (int mt = 0; mt < 2; ++mt)
#pragma unroll
        for (int nt = 0; nt < 8; ++nt) acc[mt][nt] = (floatx4)(0.0f);

    int r  = tid >> 2;
    int c8 = (tid & 3) * 8;
    int gr0 = min(row0 + r, N_NODES - 1);
    int gr1 = min(row0 + r + 64, N_NODES - 1);

    for (int k0 = 0; k0 < 640; k0 += 32) {
        *(uint4*)&sA[r * 32 + c8]        = *(const uint4*)&Xb[(size_t)gr0 * XB_COLS + k0 + c8];
        *(uint4*)&sA[(r + 64) * 32 + c8] = *(const uint4*)&Xb[(size_t)gr1 * XB_COLS + k0 + c8];
        *(uint4*)&sB[r * 32 + c8]        = *(const uint4*)&Wt[r * 640 + k0 + c8];
        *(uint4*)&sB[(r + 64) * 32 + c8] = *(const uint4*)&Wt[(r + 64) * 640 + k0 + c8];
        __syncthreads();
        short8 a0 = *(short8*)&sA[(wave * 32 + m16) * 32 + quad * 8];
        short8 a1 = *(short8*)&sA[(wave * 32 + 16 + m16) * 32 + quad * 8];
#pragma unroll
        for (int nt = 0; nt < 8; ++nt) {
            short8 b = *(short8*)&sB[(nt * 16 + m16) * 32 + quad * 8];
            acc[0][nt] = __builtin_amdgcn_mfma_f32_16x16x32_bf16(a0, b, acc[0][nt], 0, 0, 0);
            acc[1][nt] = __builtin_amdgcn_mfma_f32_16x16x32_bf16(a1, b, acc[1][nt], 0, 0, 0);
        }
        __syncthreads();
    }
#pragma unroll
    for (int nt = 0; nt < 8; ++nt) {
        int col = nt * 16 + m16;
        float bb = bias[col];
        float sv = 0.0f, sq = 0.0f;
#pragma unroll
        for (int mt = 0; mt < 2; ++mt) {
            int rbase = row0 + wave * 32 + mt * 16 + quad * 4;
#pragma unroll
            for (int reg = 0; reg < 4; ++reg) {
                int row = rbase + reg;
                if (row < N_NODES) {
                    float w = acc[mt][nt][reg] + bb;
                    out[(size_t)row * OUT_F + col] = w;
                    sv += w;
                    sq += w * w;
                }
            }
        }
        sv += __shfl_down(sv, 32); sq += __shfl_down(sq, 32);
        sv += __shfl_down(sv, 16); sq += __shfl_down(sq, 16);
        if (lane < 16) { cs[wave][col] = sv; cq[wave][col] = sq; }
    }
    __syncthreads();
    if (tid < OUT_F) {
        float s = cs[0][tid] + cs[1][tid] + cs[2][tid] + cs[3][tid];
        float q = cq[0][tid] + cq[1][tid] + cq[2][tid] + cq[3][tid];
        atomicAdd(&colsum[tid], s);
        atomicAdd(&colsq[tid], q);
    }
}

__global__ void k_bn_apply(float* __restrict__ out, const float* __restrict__ colsum,
                           const float* __restrict__ colsq, const float* __restrict__ gamma,
                           const float* __restrict__ beta) {
    int t = blockIdx.x * 256 + threadIdx.x;
    int n = t >> 5, c = t & 31;
    float4 v = *(float4*)&out[n * OUT_F + c * 4];
    float4 s = *(const float4*)&colsum[c * 4];
    float4 q = *(const float4*)&colsq[c * 4];
    float4 g = *(const float4*)&gamma[c * 4];
    float4 b = *(const float4*)&beta[c * 4];
    const float invN = 1.0f / (float)N_NODES;
    float mux = s.x * invN, muy = s.y * invN, muz = s.z * invN, muw = s.w * invN;
    float ix = rsqrtf(q.x * invN - mux * mux + BN_EPSF);
    float iy = rsqrtf(q.y * invN - muy * muy + BN_EPSF);
    float iz = rsqrtf(q.z * invN - muz * muz + BN_EPSF);
    float iw = rsqrtf(q.w * invN - muw * muw + BN_EPSF);
    v.x = fmaxf(0.0f, (v.x - mux) * ix * g.x + b.x);
    v.y = fmaxf(0.0f, (v.y - muy) * iy * g.y + b.y);
    v.z = fmaxf(0.0f, (v.z - muz) * iz * g.z + b.z);
    v.w = fmaxf(0.0f, (v.w - muw) * iw * g.w + b.w);
    *(float4*)&out[n * OUT_F + c * 4] = v;
}

extern "C" void kernel_launch(void* const* d_in, const int* in_sizes, int n_in,
                              void* d_out, int out_size, void* d_ws, size_t ws_size,
                              hipStream_t stream) {
    const float* feature    = (const float*)d_in[0];
    const float* lin_w      = (const float*)d_in[1];
    const float* lin_b      = (const float*)d_in[2];
    const float* ew0        = (const float*)d_in[3];
    const float* eb0        = (const float*)d_in[4];
    const float* ew1        = (const float*)d_in[5];
    const float* eb1        = (const float*)d_in[6];
    const float* ew2        = (const float*)d_in[7];
    const float* eb2        = (const float*)d_in[8];
    const float* bn_gamma   = (const float*)d_in[9];
    const float* bn_beta    = (const float*)d_in[10];
    const float* lambda_max = (const float*)d_in[11];
    const float* evecs      = (const float*)d_in[12];
    const float* evals      = (const float*)d_in[13];
    const int*   edge_src   = (const int*)d_in[14];
    const int*   edge_dst   = (const int*)d_in[15];

    float* out = (float*)d_out;
    float* ws  = (float*)d_ws;
    unsigned short* Xb = (unsigned short*)(ws + OFF_XB);
    unsigned short* Wt = (unsigned short*)(ws + OFF_WT);
    float* dsq      = ws + OFF_DSQRT;
    float* hs_small = ws + OFF_HS;
    float* ef       = ws + OFF_EF;
    float* colsum   = ws + OFF_COLSUM;
    float* colsq   = ws + OFF_COLSQ;
    int*   deg      = (int*)(ws + OFF_DEG);
    int*   row_start= (int*)(ws + OFF_ROWSTART);
    int*   csr_src  = (int*)(ws + OFF_CSR);
    int*   bsum     = (int*)(ws + OFF_BSUM);
    int*   rank     = (int*)(ws + OFF_RANK);
    float* partials = ws + OFF_X1F;

    // ---- prep (feat->bf16, W->Wt bf16, zero deg/stats) + CSR build ----
    k_prep<<<3674, 256, 0, stream>>>(feature, lin_w, Xb, Wt, deg, hs_small);
    k_rank<<<(N_EDGES + 255) / 256, 256, 0, stream>>>(deg, edge_dst, rank);
    k_scan1<<<SCAN_BLK, 1024, 0, stream>>>(deg, row_start, bsum);
    k_scan2<<<1, 64, 0, stream>>>(bsum);
    k_scan3<<<SCAN_BLK, 1024, 0, stream>>>(deg, row_start, bsum, dsq);
    k_csr<<<(N_EDGES + 255) / 256, 256, 0, stream>>>(edge_src, edge_dst, rank, row_start, csr_src);

    // ---- Chebyshev recurrence (all-bf16 state in Xb column slots) ----
    const int GBLK = (N_NODES * 64 + 255) / 256;
    k_gather<<<GBLK, 256, 0, stream>>>(row_start, csr_src, dsq,
                                       Xb + 0, Xb + 0, (const unsigned short*)nullptr,
                                       Xb + IN_F, lambda_max, 1);
    k_gather<<<GBLK, 256, 0, stream>>>(row_start, csr_src, dsq,
                                       Xb + IN_F, Xb + IN_F, Xb + 0,
                                       Xb + 2 * IN_F, lambda_max, 0);
    k_gather<<<GBLK, 256, 0, stream>>>(row_start, csr_src, dsq,
                                       Xb + 2 * IN_F, Xb + 2 * IN_F, Xb + IN_F,
                                       Xb + 3 * IN_F, lambda_max, 0);

    // ---- eigen block ----
    k_ef2<<<NEIG, 128, 0, stream>>>(evals, ew0, eb0, ew1, eb1, ew2, eb2, ef);
    k_hs_partial2<<<HSP_BLOCKS, 256, 0, stream>>>(evecs, feature, partials);
    k_hs_reduce<<<32 * RED_SPLIT, 256, 0, stream>>>(partials, hs_small);
    k_hs_apply2<<<(N_NODES + 31) / 32, 256, 0, stream>>>(Xb, evecs, hs_small, ef);

    // ---- MFMA linear (+BN stats) + BN apply ----
    k_gemm<<<(N_NODES + 127) / 128, 256, 0, stream>>>(Xb, Wt, lin_b, out, colsum, colsq);
    k_bn_apply<<<(N_NODES * 32) / 256, 256, 0, stream>>>(out, colsum, colsq, bn_gamma, bn_beta);
}